// Round 1
// baseline (2776.760 us; speedup 1.0000x reference)
//
#include <hip/hip_runtime.h>
#include <math.h>

#define NROWS 16384
#define DIMS  512
#define KC    8192
#define BM 32
#define BN 128
#define DK 32
#define NTHREADS 512

// ---------------------------------------------------------------------------
// K0: per-row sum of squares (in fp64) — used for both z (16384 rows) and
// embedding (8192 rows). One wave (64 lanes) per row of 512 floats.
// ---------------------------------------------------------------------------
__global__ __launch_bounds__(256)
void rowsq_kernel(const float* __restrict__ in, double* __restrict__ out, int nrows)
{
    int gtid = blockIdx.x * blockDim.x + threadIdx.x;
    int w = gtid >> 6;          // global wave id == row
    int lane = threadIdx.x & 63;
    if (w >= nrows) return;
    const float* r = in + (size_t)w * DIMS;
    float4 v0 = *(const float4*)(r + lane * 4);
    float4 v1 = *(const float4*)(r + 256 + lane * 4);
    double s = (double)v0.x * v0.x + (double)v0.y * v0.y +
               (double)v0.z * v0.z + (double)v0.w * v0.w +
               (double)v1.x * v1.x + (double)v1.y * v1.y +
               (double)v1.z * v1.z + (double)v1.w * v1.w;
    #pragma unroll
    for (int off = 32; off; off >>= 1) s += __shfl_down(s, off);
    if (lane == 0) out[w] = s;
}

// ---------------------------------------------------------------------------
// K1: fused distance GEMM + row argmin.
// Tile: BM=32 rows x BN=128 codes per chunk, all 8192 codes looped in-block.
// 512 threads: tx = t&15 -> 2 rows each; ty = t>>4 -> 4 codes each.
// LDS staged, transposed ([DK][dim]) with padding for conflict-free reads.
// ---------------------------------------------------------------------------
__global__ __launch_bounds__(NTHREADS, 4)
void dist_argmin_kernel(const float* __restrict__ z, const float* __restrict__ emb,
                        const double* __restrict__ zsq, const double* __restrict__ esq,
                        float* __restrict__ out_idx_f, int* __restrict__ counts)
{
    __shared__ float As[DK][BM + 2];    // 32 x 34 floats: 136B row stride (8B aligned)
    __shared__ float Bs[DK][BN + 4];    // 32 x 132 floats: 528B row stride (16B aligned)
    __shared__ float redv[BM][33];
    __shared__ int   redi[BM][33];

    const int t  = threadIdx.x;
    const int tx = t & 15;      // row group (2 rows)
    const int ty = t >> 4;      // col group (4 codes), 0..31
    const int row0 = blockIdx.x * BM;

    // staging maps
    const int ar = t >> 4;             // A: row 0..31
    const int as = (t & 15) * 2;       // A: d-offset 0..30
    const int bc = t >> 2;             // B: code 0..127
    const int bs = (t & 3) * 8;        // B: d-offset {0,8,16,24}

    const float* zrowA = z + (size_t)(row0 + ar) * DIMS + as;

    float minv0 = 3.4e38f, minv1 = 3.4e38f;
    int   mini0 = 0,       mini1 = 0;
    const double zs0 = zsq[row0 + tx * 2 + 0];
    const double zs1 = zsq[row0 + tx * 2 + 1];

    for (int cb = 0; cb < KC; cb += BN) {
        float acc[2][4];
        #pragma unroll
        for (int i = 0; i < 2; ++i)
            #pragma unroll
            for (int j = 0; j < 4; ++j) acc[i][j] = 0.0f;

        const float* ebase = emb + (size_t)(cb + bc) * DIMS + bs;

        for (int dk = 0; dk < DIMS; dk += DK) {
            __syncthreads();
            {   // stage A (32x32), transposed
                float2 v = *(const float2*)(zrowA + dk);
                As[as + 0][ar] = v.x;
                As[as + 1][ar] = v.y;
            }
            {   // stage B (128x32), transposed
                float4 v0 = *(const float4*)(ebase + dk);
                float4 v1 = *(const float4*)(ebase + dk + 4);
                Bs[bs + 0][bc] = v0.x; Bs[bs + 1][bc] = v0.y;
                Bs[bs + 2][bc] = v0.z; Bs[bs + 3][bc] = v0.w;
                Bs[bs + 4][bc] = v1.x; Bs[bs + 5][bc] = v1.y;
                Bs[bs + 6][bc] = v1.z; Bs[bs + 7][bc] = v1.w;
            }
            __syncthreads();
            #pragma unroll
            for (int d = 0; d < DK; ++d) {
                float2 a = *(const float2*)&As[d][tx * 2];
                float4 b = *(const float4*)&Bs[d][ty * 4];
                acc[0][0] = fmaf(a.x, b.x, acc[0][0]);
                acc[0][1] = fmaf(a.x, b.y, acc[0][1]);
                acc[0][2] = fmaf(a.x, b.z, acc[0][2]);
                acc[0][3] = fmaf(a.x, b.w, acc[0][3]);
                acc[1][0] = fmaf(a.y, b.x, acc[1][0]);
                acc[1][1] = fmaf(a.y, b.y, acc[1][1]);
                acc[1][2] = fmaf(a.y, b.z, acc[1][2]);
                acc[1][3] = fmaf(a.y, b.w, acc[1][3]);
            }
        }
        // distances + running argmin (codes ascending -> strict < keeps first)
        #pragma unroll
        for (int j = 0; j < 4; ++j) {
            int code = cb + ty * 4 + j;
            double es = esq[code];
            float d0 = (float)(zs0 + es - 2.0 * (double)acc[0][j]);
            float d1 = (float)(zs1 + es - 2.0 * (double)acc[1][j]);
            if (d0 < minv0) { minv0 = d0; mini0 = code; }
            if (d1 < minv1) { minv1 = d1; mini1 = code; }
        }
    }

    redv[tx * 2 + 0][ty] = minv0;  redi[tx * 2 + 0][ty] = mini0;
    redv[tx * 2 + 1][ty] = minv1;  redi[tx * 2 + 1][ty] = mini1;
    __syncthreads();

    if (t < BM) {
        float bv = redv[t][0];
        int   bi = redi[t][0];
        for (int y = 1; y < 32; ++y) {
            float v = redv[t][y];
            int  ii = redi[t][y];
            if (v < bv || (v == bv && ii < bi)) { bv = v; bi = ii; }
        }
        out_idx_f[row0 + t] = (float)bi;
        atomicAdd(&counts[bi], 1);
    }
}

// ---------------------------------------------------------------------------
// K2: gather quantized = embedding[idx], write to out, and accumulate
// per-block partial sums of (q - z)^2.
// ---------------------------------------------------------------------------
__global__ __launch_bounds__(256)
void gather_loss_kernel(const float* __restrict__ z, const float* __restrict__ emb,
                        const float* __restrict__ idxf, float* __restrict__ outq,
                        float* __restrict__ bsums)
{
    int gid = blockIdx.x * 256 + threadIdx.x;   // 0 .. 2097151
    int row = gid >> 7;                         // 128 float4 per row
    int c4  = (gid & 127) << 2;
    int idx = (int)idxf[row];
    float4 e  = *(const float4*)&emb[(size_t)idx * DIMS + c4];
    float4 zv = *(const float4*)&z[(size_t)row * DIMS + c4];
    *(float4*)&outq[(size_t)row * DIMS + c4] = e;
    float dx = e.x - zv.x, dy = e.y - zv.y, dz = e.z - zv.z, dw = e.w - zv.w;
    float s = dx * dx + dy * dy + dz * dz + dw * dw;
    #pragma unroll
    for (int off = 32; off; off >>= 1) s += __shfl_down(s, off);
    __shared__ float wsum[4];
    if ((threadIdx.x & 63) == 0) wsum[threadIdx.x >> 6] = s;
    __syncthreads();
    if (threadIdx.x == 0)
        bsums[blockIdx.x] = wsum[0] + wsum[1] + wsum[2] + wsum[3];
}

// ---------------------------------------------------------------------------
// K3: finalize scalars: vq_loss and perplexity.
// ---------------------------------------------------------------------------
__global__ __launch_bounds__(256)
void finalize_kernel(const int* __restrict__ counts, const float* __restrict__ bsums,
                     float* __restrict__ out_scalars)
{
    int t = threadIdx.x;
    double ls = 0.0, ps = 0.0;
    for (int i = t; i < 8192; i += 256) {
        ls += (double)bsums[i];
        double avg = (double)counts[i] * (1.0 / 16384.0);
        ps += avg * log(avg + 1e-10);
    }
    #pragma unroll
    for (int off = 32; off; off >>= 1) {
        ls += __shfl_down(ls, off);
        ps += __shfl_down(ps, off);
    }
    __shared__ double l4[4], p4[4];
    if ((t & 63) == 0) { l4[t >> 6] = ls; p4[t >> 6] = ps; }
    __syncthreads();
    if (t == 0) {
        double L = l4[0] + l4[1] + l4[2] + l4[3];
        double P = p4[0] + p4[1] + p4[2] + p4[3];
        out_scalars[0] = (float)(1.25 * L / 8388608.0);  // (1 + 0.25) * mean
        out_scalars[1] = (float)exp(-P);
    }
}

// ---------------------------------------------------------------------------
// ws layout (bytes):
//   esq   double[8192]   @ 0       (65536)
//   zsq   double[16384]  @ 65536   (131072)
//   counts int[8192]     @ 196608  (32768)
//   bsums float[8192]    @ 229376  (32768)
// total 262144 bytes
// d_out layout (floats): quantized[8388608] | vq_loss | perplexity | idx[16384]
// ---------------------------------------------------------------------------
extern "C" void kernel_launch(void* const* d_in, const int* in_sizes, int n_in,
                              void* d_out, int out_size, void* d_ws, size_t ws_size,
                              hipStream_t stream)
{
    const float* z   = (const float*)d_in[0];
    const float* emb = (const float*)d_in[1];

    float* out         = (float*)d_out;
    float* outq        = out;                   // 8388608
    float* out_scalars = out + 8388608;         // [0]=vq_loss, [1]=perplexity
    float* out_idx     = out + 8388610;         // 16384 (as float)

    char* ws = (char*)d_ws;
    double* esq   = (double*)(ws + 0);
    double* zsq   = (double*)(ws + 65536);
    int*    counts= (int*)   (ws + 196608);
    float*  bsums = (float*) (ws + 229376);

    hipMemsetAsync(counts, 0, 8192 * sizeof(int), stream);
    rowsq_kernel<<<2048, 256, 0, stream>>>(emb, esq, 8192);
    rowsq_kernel<<<4096, 256, 0, stream>>>(z, zsq, 16384);
    dist_argmin_kernel<<<NROWS / BM, NTHREADS, 0, stream>>>(z, emb, zsq, esq,
                                                            out_idx, counts);
    gather_loss_kernel<<<8192, 256, 0, stream>>>(z, emb, out_idx, outq, bsums);
    finalize_kernel<<<1, 256, 0, stream>>>(counts, bsums, out_scalars);
}

// Round 2
// 1985.182 us; speedup vs baseline: 1.3987x; 1.3987x over previous
//
#include <hip/hip_runtime.h>
#include <math.h>

#define NROWS 16384
#define DIMS  512
#define KC    8192
#define BM 128          // rows per block
#define BN 128          // cols per inner chunk
#define DK 32           // k-depth per LDS stage
#define NSPLIT 8        // col splits across blocks
#define CPS (KC / NSPLIT)   // cols per split = 1024

// ---------------------------------------------------------------------------
// K0: per-row sum of squares of embedding (accumulate fp64, store fp32).
// One wave per row of 512 floats.
// ---------------------------------------------------------------------------
__global__ __launch_bounds__(256)
void rowsq_kernel(const float* __restrict__ in, float* __restrict__ out, int nrows)
{
    int gtid = blockIdx.x * blockDim.x + threadIdx.x;
    int w = gtid >> 6;
    int lane = threadIdx.x & 63;
    if (w >= nrows) return;
    const float* r = in + (size_t)w * DIMS;
    float4 v0 = *(const float4*)(r + lane * 4);
    float4 v1 = *(const float4*)(r + 256 + lane * 4);
    double s = (double)v0.x * v0.x + (double)v0.y * v0.y +
               (double)v0.z * v0.z + (double)v0.w * v0.w +
               (double)v1.x * v1.x + (double)v1.y * v1.y +
               (double)v1.z * v1.z + (double)v1.w * v1.w;
    #pragma unroll
    for (int off = 32; off; off >>= 1) s += __shfl_down(s, off);
    if (lane == 0) out[w] = (float)s;
}

// ---------------------------------------------------------------------------
// K1: distance GEMM + argmin.  128 rows x 1024 cols per block, 8x8 register
// tile per thread (256 threads: tx=t&15 -> 8 rows, ty=t>>4 -> 8 cols).
// LDS tiles transposed [d][row]/[d][col]; strides 132/136 keep float4 reads
// 16B-aligned and transpose scalar writes at <=2-way bank aliasing.
// argmin uses v = ||e||^2 - 2 z.e  (||z||^2 constant per row, dropped).
// Per-row merge: order-preserving (f32,idx) -> u64 key, LDS pre-reduce,
// one atomicMin per row per block.
// ---------------------------------------------------------------------------
__global__ __launch_bounds__(256, 3)
void dist_argmin_kernel(const float* __restrict__ z, const float* __restrict__ emb,
                        const float* __restrict__ esf,
                        unsigned long long* __restrict__ rowkey)
{
    __shared__ __align__(16) float As[DK][BM + 4];   // [d][row], stride 132
    __shared__ __align__(16) float Bs[DK][BN + 8];   // [d][col], stride 136

    const int t  = threadIdx.x;
    const int tx = t & 15;          // 8 rows each
    const int ty = t >> 4;          // 8 cols each
    const int row0 = blockIdx.x * BM;
    const int col0 = blockIdx.y * CPS;

    const int sr  = t >> 1;         // staging row/col 0..127
    const int sc0 = (t & 1) * 16;   // staging d-offset {0,16}

    float minv[8];
    int   mini[8];
    #pragma unroll
    for (int i = 0; i < 8; ++i) { minv[i] = 3.4e38f; mini[i] = 0; }

    const float* zbase = z + (size_t)(row0 + sr) * DIMS + sc0;

    #pragma unroll 1
    for (int cb = 0; cb < CPS; cb += BN) {
        const float* ebase = emb + (size_t)(col0 + cb + sr) * DIMS + sc0;

        float acc[8][8];
        #pragma unroll
        for (int i = 0; i < 8; ++i)
            #pragma unroll
            for (int j = 0; j < 8; ++j) acc[i][j] = 0.0f;

        #pragma unroll 1
        for (int dk0 = 0; dk0 < DIMS; dk0 += DK) {
            __syncthreads();
            {   // stage A: 16 floats along d for one row, write transposed
                const float* zp = zbase + dk0;
                float4 v0 = *(const float4*)(zp + 0);
                float4 v1 = *(const float4*)(zp + 4);
                float4 v2 = *(const float4*)(zp + 8);
                float4 v3 = *(const float4*)(zp + 12);
                As[sc0 +  0][sr] = v0.x; As[sc0 +  1][sr] = v0.y;
                As[sc0 +  2][sr] = v0.z; As[sc0 +  3][sr] = v0.w;
                As[sc0 +  4][sr] = v1.x; As[sc0 +  5][sr] = v1.y;
                As[sc0 +  6][sr] = v1.z; As[sc0 +  7][sr] = v1.w;
                As[sc0 +  8][sr] = v2.x; As[sc0 +  9][sr] = v2.y;
                As[sc0 + 10][sr] = v2.z; As[sc0 + 11][sr] = v2.w;
                As[sc0 + 12][sr] = v3.x; As[sc0 + 13][sr] = v3.y;
                As[sc0 + 14][sr] = v3.z; As[sc0 + 15][sr] = v3.w;
            }
            {   // stage B: 16 floats along d for one code, write transposed
                const float* ep = ebase + dk0;
                float4 v0 = *(const float4*)(ep + 0);
                float4 v1 = *(const float4*)(ep + 4);
                float4 v2 = *(const float4*)(ep + 8);
                float4 v3 = *(const float4*)(ep + 12);
                Bs[sc0 +  0][sr] = v0.x; Bs[sc0 +  1][sr] = v0.y;
                Bs[sc0 +  2][sr] = v0.z; Bs[sc0 +  3][sr] = v0.w;
                Bs[sc0 +  4][sr] = v1.x; Bs[sc0 +  5][sr] = v1.y;
                Bs[sc0 +  6][sr] = v1.z; Bs[sc0 +  7][sr] = v1.w;
                Bs[sc0 +  8][sr] = v2.x; Bs[sc0 +  9][sr] = v2.y;
                Bs[sc0 + 10][sr] = v2.z; Bs[sc0 + 11][sr] = v2.w;
                Bs[sc0 + 12][sr] = v3.x; Bs[sc0 + 13][sr] = v3.y;
                Bs[sc0 + 14][sr] = v3.z; Bs[sc0 + 15][sr] = v3.w;
            }
            __syncthreads();

            #pragma unroll 4
            for (int d = 0; d < DK; ++d) {
                const float4 A0 = *(const float4*)&As[d][tx * 8];
                const float4 A1 = *(const float4*)&As[d][tx * 8 + 4];
                const float4 B0 = *(const float4*)&Bs[d][ty * 8];
                const float4 B1 = *(const float4*)&Bs[d][ty * 8 + 4];
                const float a[8] = {A0.x, A0.y, A0.z, A0.w, A1.x, A1.y, A1.z, A1.w};
                const float b[8] = {B0.x, B0.y, B0.z, B0.w, B1.x, B1.y, B1.z, B1.w};
                #pragma unroll
                for (int i = 0; i < 8; ++i)
                    #pragma unroll
                    for (int j = 0; j < 8; ++j)
                        acc[i][j] = fmaf(a[i], b[j], acc[i][j]);
            }
        }

        // fold chunk into running per-row argmin (cols ascending: cb asc, j asc)
        #pragma unroll
        for (int j = 0; j < 8; ++j) {
            const int col = col0 + cb + ty * 8 + j;
            const float es = esf[col];
            #pragma unroll
            for (int i = 0; i < 8; ++i) {
                float v = fmaf(-2.0f, acc[i][j], es);
                if (v < minv[i]) { minv[i] = v; mini[i] = col; }
            }
        }
    }

    // in-block reduction over ty, then one atomicMin per row
    __syncthreads();
    unsigned long long* keybuf = (unsigned long long*)&Bs[0][0];  // 128*16*8B=16KB
    #pragma unroll
    for (int i = 0; i < 8; ++i) {
        unsigned u = __float_as_uint(minv[i]);
        u = (u & 0x80000000u) ? ~u : (u | 0x80000000u);
        unsigned long long key =
            ((unsigned long long)u << 32) | (unsigned)mini[i];
        keybuf[(tx * 8 + i) * 16 + ty] = key;
    }
    __syncthreads();
    if (t < BM) {
        unsigned long long best = keybuf[t * 16];
        #pragma unroll
        for (int y = 1; y < 16; ++y) {
            unsigned long long k = keybuf[t * 16 + y];
            best = (k < best) ? k : best;
        }
        atomicMin(&rowkey[row0 + t], best);
    }
}

// ---------------------------------------------------------------------------
// K1b: decode per-row keys -> index output + histogram
// ---------------------------------------------------------------------------
__global__ __launch_bounds__(256)
void combine_kernel(const unsigned long long* __restrict__ rowkey,
                    float* __restrict__ out_idx_f, int* __restrict__ counts)
{
    int r = blockIdx.x * 256 + threadIdx.x;
    int idx = (int)(rowkey[r] & 0xFFFFFFFFull);
    out_idx_f[r] = (float)idx;
    atomicAdd(&counts[idx], 1);
}

// ---------------------------------------------------------------------------
// K2: gather quantized = embedding[idx], write out, partial (q-z)^2 sums
// ---------------------------------------------------------------------------
__global__ __launch_bounds__(256)
void gather_loss_kernel(const float* __restrict__ z, const float* __restrict__ emb,
                        const float* __restrict__ idxf, float* __restrict__ outq,
                        float* __restrict__ bsums)
{
    int gid = blockIdx.x * 256 + threadIdx.x;
    int row = gid >> 7;
    int c4  = (gid & 127) << 2;
    int idx = (int)idxf[row];
    float4 e  = *(const float4*)&emb[(size_t)idx * DIMS + c4];
    float4 zv = *(const float4*)&z[(size_t)row * DIMS + c4];
    *(float4*)&outq[(size_t)row * DIMS + c4] = e;
    float dx = e.x - zv.x, dy = e.y - zv.y, dz = e.z - zv.z, dw = e.w - zv.w;
    float s = dx * dx + dy * dy + dz * dz + dw * dw;
    #pragma unroll
    for (int off = 32; off; off >>= 1) s += __shfl_down(s, off);
    __shared__ float wsum[4];
    if ((threadIdx.x & 63) == 0) wsum[threadIdx.x >> 6] = s;
    __syncthreads();
    if (threadIdx.x == 0)
        bsums[blockIdx.x] = wsum[0] + wsum[1] + wsum[2] + wsum[3];
}

// ---------------------------------------------------------------------------
// K3: finalize scalars: vq_loss and perplexity
// ---------------------------------------------------------------------------
__global__ __launch_bounds__(256)
void finalize_kernel(const int* __restrict__ counts, const float* __restrict__ bsums,
                     float* __restrict__ out_scalars)
{
    int t = threadIdx.x;
    double ls = 0.0, ps = 0.0;
    for (int i = t; i < 8192; i += 256) {
        ls += (double)bsums[i];
        double avg = (double)counts[i] * (1.0 / 16384.0);
        ps += avg * log(avg + 1e-10);
    }
    #pragma unroll
    for (int off = 32; off; off >>= 1) {
        ls += __shfl_down(ls, off);
        ps += __shfl_down(ps, off);
    }
    __shared__ double l4[4], p4[4];
    if ((t & 63) == 0) { l4[t >> 6] = ls; p4[t >> 6] = ps; }
    __syncthreads();
    if (t == 0) {
        double L = l4[0] + l4[1] + l4[2] + l4[3];
        double P = p4[0] + p4[1] + p4[2] + p4[3];
        out_scalars[0] = (float)(1.25 * L / 8388608.0);
        out_scalars[1] = (float)exp(-P);
    }
}

// ---------------------------------------------------------------------------
// ws layout (bytes):
//   rowkey u64[16384]  @ 0       (131072)  init 0xFF each launch
//   counts int[8192]   @ 131072  (32768)   init 0
//   bsums  float[8192] @ 163840  (32768)
//   esf    float[8192] @ 196608  (32768)
// total 229376 bytes
// d_out (floats): quantized[8388608] | vq_loss | perplexity | idx[16384]
// ---------------------------------------------------------------------------
extern "C" void kernel_launch(void* const* d_in, const int* in_sizes, int n_in,
                              void* d_out, int out_size, void* d_ws, size_t ws_size,
                              hipStream_t stream)
{
    const float* z   = (const float*)d_in[0];
    const float* emb = (const float*)d_in[1];

    float* out         = (float*)d_out;
    float* outq        = out;
    float* out_scalars = out + 8388608;
    float* out_idx     = out + 8388610;

    char* ws = (char*)d_ws;
    unsigned long long* rowkey = (unsigned long long*)(ws + 0);
    int*    counts = (int*)  (ws + 131072);
    float*  bsums  = (float*)(ws + 163840);
    float*  esf    = (float*)(ws + 196608);

    hipMemsetAsync(rowkey, 0xFF, NROWS * sizeof(unsigned long long), stream);
    hipMemsetAsync(counts, 0, KC * sizeof(int), stream);

    rowsq_kernel<<<2048, 256, 0, stream>>>(emb, esf, KC);
    dist_argmin_kernel<<<dim3(NROWS / BM, NSPLIT), 256, 0, stream>>>(
        z, emb, esf, rowkey);
    combine_kernel<<<NROWS / 256, 256, 0, stream>>>(rowkey, out_idx, counts);
    gather_loss_kernel<<<8192, 256, 0, stream>>>(z, emb, out_idx, outq, bsums);
    finalize_kernel<<<1, 256, 0, stream>>>(counts, bsums, out_scalars);
}

// Round 3
// 461.741 us; speedup vs baseline: 6.0137x; 4.2993x over previous
//
#include <hip/hip_runtime.h>
#include <math.h>

typedef _Float16 half8 __attribute__((ext_vector_type(8)));
typedef float    f32x4 __attribute__((ext_vector_type(4)));

#define NROWS 16384
#define DIMS  512
#define KC    8192
#define BM 128
#define BN 128
#define BK 32

// ---------------------------------------------------------------------------
// K0: per-row sum of squares of embedding (fp64 accum, fp32 out).
// ---------------------------------------------------------------------------
__global__ __launch_bounds__(256)
void rowsq_kernel(const float* __restrict__ in, float* __restrict__ out, int nrows)
{
    int gtid = blockIdx.x * blockDim.x + threadIdx.x;
    int w = gtid >> 6;
    int lane = threadIdx.x & 63;
    if (w >= nrows) return;
    const float* r = in + (size_t)w * DIMS;
    float4 v0 = *(const float4*)(r + lane * 4);
    float4 v1 = *(const float4*)(r + 256 + lane * 4);
    double s = (double)v0.x * v0.x + (double)v0.y * v0.y +
               (double)v0.z * v0.z + (double)v0.w * v0.w +
               (double)v1.x * v1.x + (double)v1.y * v1.y +
               (double)v1.z * v1.z + (double)v1.w * v1.w;
    #pragma unroll
    for (int off = 32; off; off >>= 1) s += __shfl_down(s, off);
    if (lane == 0) out[w] = (float)s;
}

// ---------------------------------------------------------------------------
// helpers
// ---------------------------------------------------------------------------
__device__ inline void cvt16(const float4 r0, const float4 r1,
                             const float4 r2, const float4 r3,
                             half8& h0, half8& h1, half8& l0, half8& l1)
{
    float v0[8] = {r0.x, r0.y, r0.z, r0.w, r1.x, r1.y, r1.z, r1.w};
    float v1[8] = {r2.x, r2.y, r2.z, r2.w, r3.x, r3.y, r3.z, r3.w};
    #pragma unroll
    for (int i = 0; i < 8; ++i) {
        _Float16 a = (_Float16)v0[i];
        h0[i] = a;
        l0[i] = (_Float16)(v0[i] - (float)a);
        _Float16 b = (_Float16)v1[i];
        h1[i] = b;
        l1[i] = (_Float16)(v1[i] - (float)b);
    }
}

__device__ inline unsigned long long shflxor_u64(unsigned long long v, int m)
{
    int lo = __shfl_xor((int)(unsigned)(v & 0xffffffffull), m, 64);
    int hi = __shfl_xor((int)(unsigned)(v >> 32), m, 64);
    return ((unsigned long long)(unsigned)hi << 32) | (unsigned)lo;
}

// ---------------------------------------------------------------------------
// K1: distance GEMM via fp16 hi/lo split MFMA + per-row argmin.
// Block: 128 rows x 128 codes, 4 waves (each 64x64), K-step 32.
//   dot = z_hi.e_hi + z_hi.e_lo + z_lo.e_hi   (lo.lo dropped, ~5e-6)
// LDS layout [kgrp 0..3][row 0..127] of half8 -> all ds ops are b128,
// even bank spread (consecutive rows = consecutive 16B slots).
// Staging is symmetric for A and B, so any internal MFMA k-permutation
// cancels; only the C/D layout (col=lane&15, row=(lane>>4)*4+reg) matters.
// ---------------------------------------------------------------------------
__global__ __launch_bounds__(256, 2)
void dist_argmin_mfma(const float* __restrict__ z, const float* __restrict__ emb,
                      const float* __restrict__ esf,
                      unsigned long long* __restrict__ rowkey)
{
    __shared__ half8 Ah[4][BM];
    __shared__ half8 Al[4][BM];
    __shared__ half8 Bh[4][BN];
    __shared__ half8 Bl[4][BN];
    __shared__ float esl[BN];

    const int t    = threadIdx.x;
    const int lane = t & 63;
    const int wave = t >> 6;
    const int wm0  = (wave >> 1) * 64;
    const int wn0  = (wave & 1) * 64;
    const int row0 = blockIdx.x * BM;
    const int col0 = blockIdx.y * BN;

    const int srow = t >> 1;        // staged row/code 0..127
    const int kh   = t & 1;         // which 16-float half of the K-step
    const int g0   = kh * 2;        // kgrp base

    if (t < BN) esl[t] = esf[col0 + t];

    const float* za = z   + (size_t)(row0 + srow) * DIMS + kh * 16;
    const float* ea = emb + (size_t)(col0 + srow) * DIMS + kh * 16;

    f32x4 acc[4][4];
    #pragma unroll
    for (int i = 0; i < 4; ++i)
        #pragma unroll
        for (int j = 0; j < 4; ++j)
            acc[i][j] = (f32x4){0.f, 0.f, 0.f, 0.f};

    // preload K-step 0
    float4 ra0 = *(const float4*)(za + 0);
    float4 ra1 = *(const float4*)(za + 4);
    float4 ra2 = *(const float4*)(za + 8);
    float4 ra3 = *(const float4*)(za + 12);
    float4 rb0 = *(const float4*)(ea + 0);
    float4 rb1 = *(const float4*)(ea + 4);
    float4 rb2 = *(const float4*)(ea + 8);
    float4 rb3 = *(const float4*)(ea + 12);

    const int lg = lane >> 4;
    const int lr = lane & 15;

    #pragma unroll 1
    for (int s = 0; s < DIMS / BK; ++s) {
        __syncthreads();   // prior step's frag reads done before overwrite
        {
            half8 h0, h1, l0, l1;
            cvt16(ra0, ra1, ra2, ra3, h0, h1, l0, l1);
            Ah[g0 + 0][srow] = h0;  Ah[g0 + 1][srow] = h1;
            Al[g0 + 0][srow] = l0;  Al[g0 + 1][srow] = l1;
            cvt16(rb0, rb1, rb2, rb3, h0, h1, l0, l1);
            Bh[g0 + 0][srow] = h0;  Bh[g0 + 1][srow] = h1;
            Bl[g0 + 0][srow] = l0;  Bl[g0 + 1][srow] = l1;
        }
        __syncthreads();

        // issue next step's global loads early; latency hides under MFMA
        if (s + 1 < DIMS / BK) {
            const float* za2 = za + (s + 1) * BK;
            const float* ea2 = ea + (s + 1) * BK;
            ra0 = *(const float4*)(za2 + 0);
            ra1 = *(const float4*)(za2 + 4);
            ra2 = *(const float4*)(za2 + 8);
            ra3 = *(const float4*)(za2 + 12);
            rb0 = *(const float4*)(ea2 + 0);
            rb1 = *(const float4*)(ea2 + 4);
            rb2 = *(const float4*)(ea2 + 8);
            rb3 = *(const float4*)(ea2 + 12);
        }

        half8 ah[4], al[4];
        #pragma unroll
        for (int i = 0; i < 4; ++i) {
            ah[i] = Ah[lg][wm0 + i * 16 + lr];
            al[i] = Al[lg][wm0 + i * 16 + lr];
        }
        #pragma unroll
        for (int j = 0; j < 4; ++j) {
            half8 bh = Bh[lg][wn0 + j * 16 + lr];
            half8 bl = Bl[lg][wn0 + j * 16 + lr];
            #pragma unroll
            for (int i = 0; i < 4; ++i) {
                acc[i][j] = __builtin_amdgcn_mfma_f32_16x16x32_f16(ah[i], bh, acc[i][j], 0, 0, 0);
                acc[i][j] = __builtin_amdgcn_mfma_f32_16x16x32_f16(ah[i], bl, acc[i][j], 0, 0, 0);
                acc[i][j] = __builtin_amdgcn_mfma_f32_16x16x32_f16(al[i], bh, acc[i][j], 0, 0, 0);
            }
        }
    }

    // epilogue: v = ||e||^2 - 2 z.e ; per-row argmin.
    // acc[i][j] reg r: row = wm0 + i*16 + lg*4 + r ; col = wn0 + j*16 + lr
    #pragma unroll
    for (int i = 0; i < 4; ++i) {
        #pragma unroll
        for (int r = 0; r < 4; ++r) {
            float best = 3.4e38f;
            int   bc   = 0;
            #pragma unroll
            for (int j = 0; j < 4; ++j) {
                int c = wn0 + j * 16 + lr;
                float v = fmaf(-2.0f, acc[i][j][r], esl[c]);
                if (v < best) { best = v; bc = c; }   // cols ascending in j
            }
            unsigned u = __float_as_uint(best);
            u = (u & 0x80000000u) ? ~u : (u | 0x80000000u);
            unsigned long long key =
                ((unsigned long long)u << 32) | (unsigned)(col0 + bc);
            #pragma unroll
            for (int m = 1; m < 16; m <<= 1) {
                unsigned long long o = shflxor_u64(key, m);
                if (o < key) key = o;
            }
            if (lr == 0)
                atomicMin(&rowkey[row0 + wm0 + i * 16 + lg * 4 + r], key);
        }
    }
}

// ---------------------------------------------------------------------------
// K1b: decode per-row keys -> index output + histogram
// ---------------------------------------------------------------------------
__global__ __launch_bounds__(256)
void combine_kernel(const unsigned long long* __restrict__ rowkey,
                    float* __restrict__ out_idx_f, int* __restrict__ counts)
{
    int r = blockIdx.x * 256 + threadIdx.x;
    int idx = (int)(rowkey[r] & 0xFFFFFFFFull);
    out_idx_f[r] = (float)idx;
    atomicAdd(&counts[idx], 1);
}

// ---------------------------------------------------------------------------
// K2: gather quantized = embedding[idx], write out, partial (q-z)^2 sums
// ---------------------------------------------------------------------------
__global__ __launch_bounds__(256)
void gather_loss_kernel(const float* __restrict__ z, const float* __restrict__ emb,
                        const float* __restrict__ idxf, float* __restrict__ outq,
                        float* __restrict__ bsums)
{
    int gid = blockIdx.x * 256 + threadIdx.x;
    int row = gid >> 7;
    int c4  = (gid & 127) << 2;
    int idx = (int)idxf[row];
    float4 e  = *(const float4*)&emb[(size_t)idx * DIMS + c4];
    float4 zv = *(const float4*)&z[(size_t)row * DIMS + c4];
    *(float4*)&outq[(size_t)row * DIMS + c4] = e;
    float dx = e.x - zv.x, dy = e.y - zv.y, dz = e.z - zv.z, dw = e.w - zv.w;
    float s = dx * dx + dy * dy + dz * dz + dw * dw;
    #pragma unroll
    for (int off = 32; off; off >>= 1) s += __shfl_down(s, off);
    __shared__ float wsum[4];
    if ((threadIdx.x & 63) == 0) wsum[threadIdx.x >> 6] = s;
    __syncthreads();
    if (threadIdx.x == 0)
        bsums[blockIdx.x] = wsum[0] + wsum[1] + wsum[2] + wsum[3];
}

// ---------------------------------------------------------------------------
// K3: finalize scalars: vq_loss and perplexity
// ---------------------------------------------------------------------------
__global__ __launch_bounds__(256)
void finalize_kernel(const int* __restrict__ counts, const float* __restrict__ bsums,
                     float* __restrict__ out_scalars)
{
    int t = threadIdx.x;
    double ls = 0.0, ps = 0.0;
    for (int i = t; i < 8192; i += 256) {
        ls += (double)bsums[i];
        double avg = (double)counts[i] * (1.0 / 16384.0);
        ps += avg * log(avg + 1e-10);
    }
    #pragma unroll
    for (int off = 32; off; off >>= 1) {
        ls += __shfl_down(ls, off);
        ps += __shfl_down(ps, off);
    }
    __shared__ double l4[4], p4[4];
    if ((t & 63) == 0) { l4[t >> 6] = ls; p4[t >> 6] = ps; }
    __syncthreads();
    if (t == 0) {
        double L = l4[0] + l4[1] + l4[2] + l4[3];
        double P = p4[0] + p4[1] + p4[2] + p4[3];
        out_scalars[0] = (float)(1.25 * L / 8388608.0);
        out_scalars[1] = (float)exp(-P);
    }
}

// ---------------------------------------------------------------------------
// ws layout (bytes):
//   rowkey u64[16384]  @ 0       (131072)  init 0xFF each launch
//   counts int[8192]   @ 131072  (32768)   init 0
//   bsums  float[8192] @ 163840  (32768)
//   esf    float[8192] @ 196608  (32768)
// total 229376 bytes
// d_out (floats): quantized[8388608] | vq_loss | perplexity | idx[16384]
// ---------------------------------------------------------------------------
extern "C" void kernel_launch(void* const* d_in, const int* in_sizes, int n_in,
                              void* d_out, int out_size, void* d_ws, size_t ws_size,
                              hipStream_t stream)
{
    const float* z   = (const float*)d_in[0];
    const float* emb = (const float*)d_in[1];

    float* out         = (float*)d_out;
    float* outq        = out;
    float* out_scalars = out + 8388608;
    float* out_idx     = out + 8388610;

    char* ws = (char*)d_ws;
    unsigned long long* rowkey = (unsigned long long*)(ws + 0);
    int*    counts = (int*)  (ws + 131072);
    float*  bsums  = (float*)(ws + 163840);
    float*  esf    = (float*)(ws + 196608);

    hipMemsetAsync(rowkey, 0xFF, NROWS * sizeof(unsigned long long), stream);
    hipMemsetAsync(counts, 0, KC * sizeof(int), stream);

    rowsq_kernel<<<2048, 256, 0, stream>>>(emb, esf, KC);
    dist_argmin_mfma<<<dim3(NROWS / BM, KC / BN), 256, 0, stream>>>(
        z, emb, esf, rowkey);
    combine_kernel<<<NROWS / 256, 256, 0, stream>>>(rowkey, out_idx, counts);
    gather_loss_kernel<<<8192, 256, 0, stream>>>(z, emb, out_idx, outq, bsums);
    finalize_kernel<<<1, 256, 0, stream>>>(counts, bsums, out_scalars);
}